// Round 10
// baseline (182.493 us; speedup 1.0000x reference)
//
#include <hip/hip_runtime.h>
#include <hip/hip_bf16.h>

constexpr int NB  = 2;
constexpr int SL  = 2048;
constexpr int EMB = 1024;
constexpr int NH  = 16;
constexpr int HD  = 64;
constexpr size_t PROJ = (size_t)NB * SL * EMB;  // 4M elements

typedef __attribute__((ext_vector_type(8))) short bf16x8;  // 8 bf16 (4 VGPRs)
typedef __attribute__((ext_vector_type(4))) float f32x4;   // MFMA C/D frag

__device__ inline short f2b(float f) {
  __hip_bfloat16 b = __float2bfloat16(f);
  short s; __builtin_memcpy(&s, &b, 2); return s;
}

__device__ inline bf16x8 pack8(f32x4 u, f32x4 v) {
  bf16x8 r;
  r[0] = f2b(u[0]); r[1] = f2b(u[1]); r[2] = f2b(u[2]); r[3] = f2b(u[3]);
  r[4] = f2b(v[0]); r[5] = f2b(v[1]); r[6] = f2b(v[2]); r[7] = f2b(v[3]);
  return r;
}

#define GLDS16(g, l)                                                     \
  __builtin_amdgcn_global_load_lds(                                      \
      (const __attribute__((address_space(1))) void*)(g),                \
      (__attribute__((address_space(3))) void*)(l), 16, 0, 0)

// ---------------------------------------------------------------------------
// QKV GEMM, fp32-direct staging (cast kernel fused away):
// C = x[4096][1024](f32) @ Wsel[1024][1024](f32)^T, bf16 MFMA after in-reg
// f2b conversion (same f2b as the old cast -> bit-identical results).
// 128x128 tile, BK=32, LDS = 2 x 128x32 f32 = 32 KB. Row = 128 B = 8 chunks
// of 16 B, so the verified involutive chunk-XOR swizzle (chunk ^= row&7)
// carries over unchanged: linear GLDS dest + inverse-swizzled fp32 global
// source + swizzled f32x4 reads. Grid 24x32; region (n0>>10) picks Wq/Wk/Wv.
// Epilogues unchanged (verified): Q*(log2e/32) row-major; K frag-blocked;
// V frag-blocked with PV key-permutation folded.
// ---------------------------------------------------------------------------
__global__ __launch_bounds__(256) void gemm_qkv(
    const float* __restrict__ x,  const float* __restrict__ Wq,
    const float* __restrict__ Wk, const float* __restrict__ Wv,
    short* __restrict__ qb, short* __restrict__ kb, short* __restrict__ vt) {
  __shared__ float Asf[128 * 32];
  __shared__ float Bsf[128 * 32];
  const int tid = threadIdx.x;
  const int w = tid >> 6, lane = tid & 63;
  const int la = lane >> 4, lb = lane & 15;
  const int wm = w & 1, wn = w >> 1;
  const int m0 = blockIdx.y << 7, n0 = blockIdx.x << 7;
  const int region = n0 >> 10;
  const float* Wsel = (region == 0) ? Wq : (region == 1) ? Wk : Wv;
  const int nb0 = n0 & 1023;
  // staging: wave w owns rows [32w,32w+32), 4 GLDS of 8 rows each.
  // lane -> row 8g+(lane>>3), chunk lane&7 (16B = 4 floats); row&7 == lane>>3
  // -> inverse-swizzled global chunk = (lane&7)^(lane>>3).
  const int srow = lane >> 3;
  const int scol = ((lane & 7) ^ srow) << 2;  // floats
  const float* a0 = x + (size_t)(m0 + w * 32 + srow) * 1024 + scol;
  const float* b0 = Wsel + (size_t)(nb0 + w * 32 + srow) * 1024 + scol;
  float* lAw = Asf + (w * 32) * 32;
  float* lBw = Bsf + (w * 32) * 32;

  f32x4 acc[4][4];
#pragma unroll
  for (int i = 0; i < 4; ++i)
#pragma unroll
    for (int j = 0; j < 4; ++j) acc[i][j] = (f32x4){0.f, 0.f, 0.f, 0.f};

  for (int k0 = 0; k0 < 1024; k0 += 32) {
    __syncthreads();
#pragma unroll
    for (int g = 0; g < 4; ++g) GLDS16(a0 + g * 8 * 1024 + k0, lAw + g * 8 * 32);
#pragma unroll
    for (int g = 0; g < 4; ++g) GLDS16(b0 + g * 8 * 1024 + k0, lBw + g * 8 * 32);
    __syncthreads();
    bf16x8 af[4], bfr[4];
#pragma unroll
    for (int i = 0; i < 4; ++i) {
      const int row = wm * 64 + i * 16 + lb;
      const f32x4 u = *(const f32x4*)&Asf[row * 32 + ((2 * la) ^ (row & 7)) * 4];
      const f32x4 v =
          *(const f32x4*)&Asf[row * 32 + ((2 * la + 1) ^ (row & 7)) * 4];
      af[i] = pack8(u, v);
    }
#pragma unroll
    for (int j = 0; j < 4; ++j) {
      const int row = wn * 64 + j * 16 + lb;
      const f32x4 u = *(const f32x4*)&Bsf[row * 32 + ((2 * la) ^ (row & 7)) * 4];
      const f32x4 v =
          *(const f32x4*)&Bsf[row * 32 + ((2 * la + 1) ^ (row & 7)) * 4];
      bfr[j] = pack8(u, v);
    }
#pragma unroll
    for (int i = 0; i < 4; ++i)
#pragma unroll
      for (int j = 0; j < 4; ++j)
        acc[i][j] = __builtin_amdgcn_mfma_f32_16x16x32_bf16(af[i], bfr[j],
                                                            acc[i][j], 0, 0, 0);
  }

  if (region == 0) {
    const float sc = 0.03125f * 1.44269504f;  // 1/sqrt(1024) * log2(e)
#pragma unroll
    for (int j = 0; j < 4; ++j) {
      const int nj = nb0 + wn * 64 + j * 16 + lb;
#pragma unroll
      for (int i = 0; i < 4; ++i) {
        const int mi = m0 + wm * 64 + i * 16 + la * 4;
#pragma unroll
        for (int r = 0; r < 4; ++r)
          qb[(size_t)(mi + r) * 1024 + nj] = f2b(acc[i][j][r] * sc);
      }
    }
  } else if (region == 1) {
    // K fragment-blocked
#pragma unroll
    for (int j = 0; j < 4; ++j) {
      const int nj = nb0 + wn * 64 + j * 16 + lb;
      const int hh = nj >> 6, d = nj & 63;
      const int ks = d >> 5, Gd = (d >> 3) & 3, jj = d & 7;
#pragma unroll
      for (int i = 0; i < 4; ++i) {
        const int mi = m0 + wm * 64 + i * 16 + la * 4;
        const int nbi = mi >> 11, seq = mi & (SL - 1);
        const size_t base = ((size_t)(nbi * NH + hh) << 17) +
                            (size_t)(seq >> 4) * 1024 + ks * 512 + Gd * 128 +
                            (seq & 15) * 8 + jj;
#pragma unroll
        for (int r = 0; r < 4; ++r) kb[base + r * 8] = f2b(acc[i][j][r]);
      }
    }
  } else {
    // V fragment-blocked (PV key-permutation folded in)
#pragma unroll
    for (int j = 0; j < 4; ++j) {
      const int nv = nb0 + wn * 64 + j * 16 + lb;
      const int hh = nv >> 6, d = nv & 63;
      const int mtd = d >> 4, lbv = d & 15;
#pragma unroll
      for (int i = 0; i < 4; ++i) {
        const int mi = m0 + wm * 64 + i * 16 + la * 4;
        const int nbi = mi >> 11, seq = mi & (SL - 1);
        const int kq = seq >> 5, g = (seq >> 2) & 3, hi = (seq >> 4) & 1;
        const short4 o = {f2b(acc[i][j][0]), f2b(acc[i][j][1]),
                          f2b(acc[i][j][2]), f2b(acc[i][j][3])};
        *(short4*)&vt[((size_t)(nbi * NH + hh) << 17) + (size_t)kq * 2048 +
                      mtd * 512 + g * 128 + lbv * 8 + 4 * hi] = o;
      }
    }
  }
}

// ---------------------------------------------------------------------------
// Out GEMM, fp32-direct B staging: out = ab[4096][1024](bf16) @
// Wo[1024][1024](f32)^T + bias, fp32 out. A stays bf16 GLDS (verified R5
// pattern); B staged fp32 (64 rows x 64 k = 16 KB), row = 256 B = 16 chunks,
// XOR swizzle on low 3 chunk bits. 128m x 64n tile, BK=64, grid 16x32 = 512
// blocks (2/CU so barrier drains overlap).
// ---------------------------------------------------------------------------
__global__ __launch_bounds__(256) void gemm_out(
    const short* __restrict__ A, const float* __restrict__ Wo,
    const float* __restrict__ bias, float* __restrict__ out) {
  __shared__ short As[128 * 64];
  __shared__ float Bsf[64 * 64];
  const int tid = threadIdx.x;
  const int w = tid >> 6, lane = tid & 63;
  const int la = lane >> 4, lb = lane & 15;
  const int wm = w & 1, wn = w >> 1;
  const int m0 = blockIdx.y << 7, n0 = blockIdx.x << 6;
  // A staging (bf16): wave w rows [32w,+32), 4 GLDS of 8 rows (128 B rows).
  const int srow = lane >> 3;
  const int scol = ((lane & 7) ^ srow) << 3;  // shorts
  const short* a0 = A + (size_t)(m0 + w * 32 + srow) * 1024 + scol;
  short* lAw = As + (w * 32) * 64;
  // B staging (fp32): wave w rows [16w,+16), 4 GLDS of 4 rows (256 B rows).
  // lane -> row 4g+(lane>>4), chunk lane&15; row&7 = 4(g&1)+(lane>>4).
  const int brow = lane >> 4;  // 0..3
  float* lBw = Bsf + (w * 16) * 64;

  f32x4 acc[4][2];
#pragma unroll
  for (int i = 0; i < 4; ++i)
#pragma unroll
    for (int j = 0; j < 2; ++j) acc[i][j] = (f32x4){0.f, 0.f, 0.f, 0.f};

  for (int k0 = 0; k0 < 1024; k0 += 64) {
    __syncthreads();
#pragma unroll
    for (int g = 0; g < 4; ++g) GLDS16(a0 + g * 8 * 1024 + k0, lAw + g * 8 * 64);
#pragma unroll
    for (int g = 0; g < 4; ++g) {
      const int rsw = 4 * (g & 1) + brow;               // row&7 of this lane
      const int bchunk = (lane & 15) ^ rsw;             // inverse-swizzled src
      const float* bsrc = Wo +
          (size_t)(n0 + w * 16 + g * 4 + brow) * 1024 + k0 + bchunk * 4;
      GLDS16(bsrc, lBw + g * 4 * 64);
    }
    __syncthreads();
#pragma unroll
    for (int ks = 0; ks < 2; ++ks) {
      bf16x8 af[4], bfr[2];
#pragma unroll
      for (int i = 0; i < 4; ++i) {
        const int row = wm * 64 + i * 16 + lb;
        af[i] = *(const bf16x8*)&As[row * 64 + (((ks << 2) + la) ^ (row & 7)) * 8];
      }
#pragma unroll
      for (int j = 0; j < 2; ++j) {
        const int row = wn * 32 + j * 16 + lb;
        const f32x4 u = *(const f32x4*)&Bsf[row * 64 +
                                            ((8 * ks + 2 * la) ^ (row & 7)) * 4];
        const f32x4 v = *(const f32x4*)&Bsf[row * 64 +
                                            ((8 * ks + 2 * la + 1) ^ (row & 7)) * 4];
        bfr[j] = pack8(u, v);
      }
#pragma unroll
      for (int i = 0; i < 4; ++i)
#pragma unroll
        for (int j = 0; j < 2; ++j)
          acc[i][j] = __builtin_amdgcn_mfma_f32_16x16x32_bf16(af[i], bfr[j],
                                                              acc[i][j], 0, 0, 0);
    }
  }
#pragma unroll
  for (int j = 0; j < 2; ++j) {
    const int nj = n0 + wn * 32 + j * 16 + lb;
    const float bv = bias[nj];
#pragma unroll
    for (int i = 0; i < 4; ++i) {
      const int mi = m0 + wm * 64 + i * 16 + la * 4;
#pragma unroll
      for (int r = 0; r < 4; ++r)
        out[(size_t)(mi + r) * 1024 + nj] = acc[i][j][r] + bv;
    }
  }
}

// ---------------------------------------------------------------------------
// Flash attention v9 (best-measured variant, frozen): zero-LDS main loop,
// direct global->register K/V (fragment-blocked), 2x-unrolled static
// ping-pong, setprio around MFMA clusters. 128 q-rows/block, 2wq x 2wk,
// grid (NH, SL/128, NB) = 512 blocks.
// ---------------------------------------------------------------------------
#define LOADK(DK, KB32)                                                      \
  do {                                                                       \
    _Pragma("unroll") for (int rr_ = 0; rr_ < 2; ++rr_)                      \
        _Pragma("unroll") for (int ks_ = 0; ks_ < 2; ++ks_)                  \
            DK[rr_][ks_] = *(const bf16x8*)(Kb + (size_t)(KB32) * 2048 +     \
                                            rr_ * 1024 + ks_ * 512);         \
  } while (0)

#define LOADV(DV, KB32)                                                      \
  do {                                                                       \
    _Pragma("unroll") for (int md_ = 0; md_ < 4; ++md_)                      \
        DV[md_] = *(const bf16x8*)(Vb + (size_t)(KB32) * 2048 + md_ * 512);  \
  } while (0)

#define ATTN_STEP(AK, AV)                                                    \
  do {                                                                       \
    f32x4 S[2][4];                                                           \
    _Pragma("unroll") for (int mt = 0; mt < 2; ++mt)                         \
        _Pragma("unroll") for (int nt = 0; nt < 4; ++nt)                     \
            S[mt][nt] = (f32x4){0.f, 0.f, 0.f, 0.f};                         \
    __builtin_amdgcn_s_setprio(1);                                           \
    _Pragma("unroll") for (int ks = 0; ks < 2; ++ks)                         \
        _Pragma("unroll") for (int nt = 0; nt < 4; ++nt) {                   \
      S[0][nt] = __builtin_amdgcn_mfma_f32_16x16x32_bf16(AK[0][ks],          \
                     bQ[nt][ks], S[0][nt], 0, 0, 0);                         \
      S[1][nt] = __builtin_amdgcn_mfma_f32_16x16x32_bf16(AK[1][ks],          \
                     bQ[nt][ks], S[1][nt], 0, 0, 0);                         \
    }                                                                        \
    __builtin_amdgcn_s_setprio(0);                                           \
    _Pragma("unroll") for (int nt = 0; nt < 4; ++nt) {                       \
      _Pragma("unroll") for (int mt = 0; mt < 2; ++mt)                       \
          _Pragma("unroll") for (int r = 0; r < 4; ++r) {                    \
        const float p = __builtin_amdgcn_exp2f(S[mt][nt][r]);                \
        S[mt][nt][r] = p;                                                    \
        lacc[nt] += p;                                                       \
      }                                                                      \
      bf16x8 B2;                                                             \
      B2[0] = f2b(S[0][nt][0]); B2[1] = f2b(S[0][nt][1]);                    \
      B2[2] = f2b(S[0][nt][2]); B2[3] = f2b(S[0][nt][3]);                    \
      B2[4] = f2b(S[1][nt][0]); B2[5] = f2b(S[1][nt][1]);                    \
      B2[6] = f2b(S[1][nt][2]); B2[7] = f2b(S[1][nt][3]);                    \
      __builtin_amdgcn_s_setprio(1);                                         \
      _Pragma("unroll") for (int mtd = 0; mtd < 4; ++mtd)                    \
          O[mtd][nt] = __builtin_amdgcn_mfma_f32_16x16x32_bf16(              \
              AV[mtd], B2, O[mtd][nt], 0, 0, 0);                             \
      __builtin_amdgcn_s_setprio(0);                                         \
    }                                                                        \
  } while (0)

__global__ __launch_bounds__(256, 2) void attn_mfma(const short* __restrict__ Qg,
                                                    const short* __restrict__ Kp,
                                                    const short* __restrict__ Vp,
                                                    short* __restrict__ Ab) {
  __shared__ __align__(16) float red[2][64][68];  // 34816 B
  __shared__ float lred[128];
  const int tid = threadIdx.x;
  const int w = tid >> 6, lane = tid & 63;
  const int G = lane >> 4, lb = lane & 15;
  const int wk = w & 1, wq = w >> 1;
  const int h = blockIdx.x, qt = blockIdx.y, n = blockIdx.z;

  // ---- Q fragments: global -> regs, once. q = 64wq+16nt+lb, d = 32ks+8G
  const short* Qb = Qg + ((size_t)(n * SL + (qt << 7) + 64 * wq)) * EMB + h * HD;
  bf16x8 bQ[4][2];
#pragma unroll
  for (int nt = 0; nt < 4; ++nt)
#pragma unroll
    for (int ks = 0; ks < 2; ++ks)
      bQ[nt][ks] =
          *(const bf16x8*)(Qb + (size_t)(16 * nt + lb) * EMB + 32 * ks + 8 * G);

  f32x4 O[4][4];  // [mtd: d=16mtd+4G+r][nt: q=64wq+16nt+lb]
  float lacc[4] = {0.f, 0.f, 0.f, 0.f};
#pragma unroll
  for (int i = 0; i < 4; ++i)
#pragma unroll
    for (int j = 0; j < 4; ++j) O[i][j] = (f32x4){0.f, 0.f, 0.f, 0.f};

  // fragment-blocked bases; fold per-lane 16B chunk offset into the pointer
  const short* Kb = Kp + (((size_t)(n * NH + h)) << 17) + lane * 8;
  const short* Vb = Vp + (((size_t)(n * NH + h)) << 17) + lane * 8;

  // wave wk owns 32-key blocks kb32 = 4j + 2wk + {0,1}; 2x-unrolled ping-pong
  bf16x8 K0[2][2], V0[4], K1[2][2], V1[4];
  LOADK(K0, 2 * wk);
  LOADV(V0, 2 * wk);
  for (int it = 0; it < 32; it += 2) {
    const int kA = 2 * it + 2 * wk;  // even sub-round's kb32
    LOADK(K1, kA + 1);
    LOADV(V1, kA + 1);
    ATTN_STEP(K0, V0);
    if (it + 2 < 32) {
      LOADK(K0, kA + 4);
      LOADV(V0, kA + 4);
    }
    ATTN_STEP(K1, V1);
  }

  // ---- finish l: reduce across G groups (sum over this wave's keys)
#pragma unroll
  for (int nt = 0; nt < 4; ++nt) {
    lacc[nt] += __shfl_xor(lacc[nt], 16);
    lacc[nt] += __shfl_xor(lacc[nt], 32);
  }

  // ---- 2-way cross-wave reduction over wk (dedicated LDS, one barrier)
  if (wk == 1) {
#pragma unroll
    for (int nt = 0; nt < 4; ++nt) {
      const int q = 16 * nt + lb;
#pragma unroll
      for (int mtd = 0; mtd < 4; ++mtd)
        *(f32x4*)&red[wq][q][16 * mtd + 4 * G] = O[mtd][nt];
      if (G == 0) lred[wq * 64 + q] = lacc[nt];
    }
  }
  __syncthreads();
  if (wk == 0) {
    short* Ao = Ab + ((size_t)(n * SL + (qt << 7) + 64 * wq)) * EMB + h * HD;
#pragma unroll
    for (int nt = 0; nt < 4; ++nt) {
      const int q = 16 * nt + lb;
      const float inv = 1.f / (lacc[nt] + lred[wq * 64 + q]);
#pragma unroll
      for (int mtd = 0; mtd < 4; ++mtd) {
        const f32x4 t = *(const f32x4*)&red[wq][q][16 * mtd + 4 * G];
        const f32x4 s = t + O[mtd][nt];
        const short4 o = {f2b(s[0] * inv), f2b(s[1] * inv), f2b(s[2] * inv),
                          f2b(s[3] * inv)};
        *(short4*)(Ao + (size_t)q * EMB + 16 * mtd + 4 * G) = o;
      }
    }
  }
}

extern "C" void kernel_launch(void* const* d_in, const int* in_sizes, int n_in,
                              void* d_out, int out_size, void* d_ws, size_t ws_size,
                              hipStream_t stream) {
  const float* x  = (const float*)d_in[0];
  const float* Wq = (const float*)d_in[1];
  const float* Wk = (const float*)d_in[2];
  const float* Wv = (const float*)d_in[3];
  const float* Wo = (const float*)d_in[4];
  const float* bo = (const float*)d_in[5];
  float* out = (float*)d_out;

  // ws (bf16 elements): qb 4M | kb 4M | vt 4M = 24 MB (cast buffers gone)
  short* qb = (short*)d_ws;
  short* kb = qb + PROJ;
  short* vt = kb + PROJ;
  short* ab = qb;  // alias: block-disjoint read-then-write regions

  gemm_qkv<<<dim3(24, 32), 256, 0, stream>>>(x, Wq, Wk, Wv, qb, kb, vt);
  attn_mfma<<<dim3(NH, SL / 128, NB), 256, 0, stream>>>(qb, kb, vt, ab);
  gemm_out<<<dim3(16, 32), 256, 0, stream>>>(ab, Wo, bo, out);
}

// Round 11
// 173.166 us; speedup vs baseline: 1.0539x; 1.0539x over previous
//
#include <hip/hip_runtime.h>
#include <hip/hip_bf16.h>

constexpr int NB  = 2;
constexpr int SL  = 2048;
constexpr int EMB = 1024;
constexpr int NH  = 16;
constexpr int HD  = 64;
constexpr int MT  = NB * SL;               // 4096 rows for projection GEMMs
constexpr size_t PROJ = (size_t)MT * EMB;  // 4M elements per [N,L,E] buffer

typedef __attribute__((ext_vector_type(8))) short bf16x8;  // 8 bf16 (4 VGPRs)
typedef __attribute__((ext_vector_type(4))) float f32x4;   // MFMA C/D frag

__device__ inline short f2b(float f) {
  __hip_bfloat16 b = __float2bfloat16(f);
  short s; __builtin_memcpy(&s, &b, 2); return s;
}

#define GLDS16(g, l)                                                     \
  __builtin_amdgcn_global_load_lds(                                      \
      (const __attribute__((address_space(1))) void*)(g),                \
      (__attribute__((address_space(3))) void*)(l), 16, 0, 0)

// ---------------------------------------------------------------------------
// Cast fp32 -> bf16: x -> xb, {Wq,Wk,Wv} -> wqkv (concat rows), Wo -> wob.
// (R10 showed fusing this into the GEMMs is net-negative: fp32 tile re-reads
// cost more than the one-shot 2x compression here.)
// ---------------------------------------------------------------------------
__global__ __launch_bounds__(256) void cast_all(
    const float* __restrict__ x,  const float* __restrict__ wq,
    const float* __restrict__ wk, const float* __restrict__ wv,
    const float* __restrict__ wo, short* __restrict__ xb,
    short* __restrict__ wqkv, short* __restrict__ wob) {
  const size_t t = (size_t)blockIdx.x * 256 + threadIdx.x;  // float4 index
  const float* src; short* dst; size_t base;
  if (t < 1048576)      { src = x;  dst = xb;              base = 0; }
  else if (t < 1310720) { src = wq; dst = wqkv;            base = 1048576; }
  else if (t < 1572864) { src = wk; dst = wqkv + (1 << 20); base = 1310720; }
  else if (t < 1835008) { src = wv; dst = wqkv + (2 << 20); base = 1572864; }
  else                  { src = wo; dst = wob;             base = 1835008; }
  const size_t i = t - base;
  const float4 v = ((const float4*)src)[i];
  const short4 o = {f2b(v.x), f2b(v.y), f2b(v.z), f2b(v.w)};
  ((short4*)dst)[i] = o;
}

// ---------------------------------------------------------------------------
// QKV GEMM (verified, best-measured): C = x[4096][1024] @ wqkv[3072][1024]^T.
// 128x128 tile, BK=64 (32 MFMA per barrier pair), grid 24x32 = 768 blocks
// (3/CU). Involutive 16B-chunk XOR swizzle (chunk ^= row&7): linear
// global_load_lds dest + inverse-swizzled per-lane GLOBAL source + swizzled
// read index (rule #21). Epilogue per n-region:
//   0 -> Q * (log2e/32), row-major;  1 -> K fragment-blocked;
//   2 -> V fragment-blocked (PV key-permutation folded).
// ---------------------------------------------------------------------------
__global__ __launch_bounds__(256) void gemm_qkv(
    const short* __restrict__ A, const short* __restrict__ W,
    short* __restrict__ qb, short* __restrict__ kb, short* __restrict__ vt) {
  __shared__ short As[128 * 64];
  __shared__ short Bs[128 * 64];
  const int tid = threadIdx.x;
  const int w = tid >> 6, lane = tid & 63;
  const int la = lane >> 4, lb = lane & 15;
  const int wm = w & 1, wn = w >> 1;
  const int m0 = blockIdx.y << 7, n0 = blockIdx.x << 7;
  const int srow = lane >> 3;
  const int scol = ((lane & 7) ^ srow) << 3;  // shorts
  const short* a0 = A + (size_t)(m0 + w * 32 + srow) * 1024 + scol;
  const short* b0 = W + (size_t)(n0 + w * 32 + srow) * 1024 + scol;
  short* lAw = As + (w * 32) * 64;
  short* lBw = Bs + (w * 32) * 64;

  f32x4 acc[4][4];
#pragma unroll
  for (int i = 0; i < 4; ++i)
#pragma unroll
    for (int j = 0; j < 4; ++j) acc[i][j] = (f32x4){0.f, 0.f, 0.f, 0.f};

  for (int k0 = 0; k0 < 1024; k0 += 64) {
    __syncthreads();
#pragma unroll
    for (int g = 0; g < 4; ++g) GLDS16(a0 + g * 8 * 1024 + k0, lAw + g * 8 * 64);
#pragma unroll
    for (int g = 0; g < 4; ++g) GLDS16(b0 + g * 8 * 1024 + k0, lBw + g * 8 * 64);
    __syncthreads();
#pragma unroll
    for (int ks = 0; ks < 2; ++ks) {
      bf16x8 af[4], bfr[4];
#pragma unroll
      for (int i = 0; i < 4; ++i) {
        const int row = wm * 64 + i * 16 + lb;
        af[i] = *(const bf16x8*)&As[row * 64 + (((ks << 2) + la) ^ (row & 7)) * 8];
      }
#pragma unroll
      for (int j = 0; j < 4; ++j) {
        const int row = wn * 64 + j * 16 + lb;
        bfr[j] = *(const bf16x8*)&Bs[row * 64 + (((ks << 2) + la) ^ (row & 7)) * 8];
      }
#pragma unroll
      for (int i = 0; i < 4; ++i)
#pragma unroll
        for (int j = 0; j < 4; ++j)
          acc[i][j] = __builtin_amdgcn_mfma_f32_16x16x32_bf16(af[i], bfr[j],
                                                              acc[i][j], 0, 0, 0);
    }
  }

  const int region = n0 >> 10;  // block-uniform (n-tile 128 < 1024)
  if (region == 0) {
    const float sc = 0.03125f * 1.44269504f;  // 1/sqrt(1024) * log2(e)
#pragma unroll
    for (int j = 0; j < 4; ++j) {
      const int nj = (n0 & 1023) + wn * 64 + j * 16 + lb;
#pragma unroll
      for (int i = 0; i < 4; ++i) {
        const int mi = m0 + wm * 64 + i * 16 + la * 4;
#pragma unroll
        for (int r = 0; r < 4; ++r)
          qb[(size_t)(mi + r) * 1024 + nj] = f2b(acc[i][j][r] * sc);
      }
    }
  } else if (region == 1) {
    // K fragment-blocked
#pragma unroll
    for (int j = 0; j < 4; ++j) {
      const int nj = (n0 & 1023) + wn * 64 + j * 16 + lb;
      const int hh = nj >> 6, d = nj & 63;
      const int ks = d >> 5, Gd = (d >> 3) & 3, jj = d & 7;
#pragma unroll
      for (int i = 0; i < 4; ++i) {
        const int mi = m0 + wm * 64 + i * 16 + la * 4;
        const int nbi = mi >> 11, seq = mi & (SL - 1);
        const size_t base = ((size_t)(nbi * NH + hh) << 17) +
                            (size_t)(seq >> 4) * 1024 + ks * 512 + Gd * 128 +
                            (seq & 15) * 8 + jj;
#pragma unroll
        for (int r = 0; r < 4; ++r) kb[base + r * 8] = f2b(acc[i][j][r]);
      }
    }
  } else {
    // V fragment-blocked (PV key-permutation folded in)
#pragma unroll
    for (int j = 0; j < 4; ++j) {
      const int nv = (n0 - 2048) + wn * 64 + j * 16 + lb;
      const int hh = nv >> 6, d = nv & 63;
      const int mtd = d >> 4, lbv = d & 15;
#pragma unroll
      for (int i = 0; i < 4; ++i) {
        const int mi = m0 + wm * 64 + i * 16 + la * 4;
        const int nbi = mi >> 11, seq = mi & (SL - 1);
        const int kq = seq >> 5, g = (seq >> 2) & 3, hi = (seq >> 4) & 1;
        const short4 o = {f2b(acc[i][j][0]), f2b(acc[i][j][1]),
                          f2b(acc[i][j][2]), f2b(acc[i][j][3])};
        *(short4*)&vt[((size_t)(nbi * NH + hh) << 17) + (size_t)kq * 2048 +
                      mtd * 512 + g * 128 + lbv * 8 + 4 * hi] = o;
      }
    }
  }
}

// ---------------------------------------------------------------------------
// Out GEMM (verified): out = ab[4096][1024](bf16) @ wob[1024][1024]^T + bias,
// fp32 out. 128m x 64n tile, BK=64, chunk-XOR swizzle, grid 16x32 = 512
// blocks (2/CU so barrier drains overlap).
// ---------------------------------------------------------------------------
__global__ __launch_bounds__(256) void gemm_out(
    const short* __restrict__ A, const short* __restrict__ W,
    const float* __restrict__ bias, float* __restrict__ out) {
  __shared__ short As[128 * 64];
  __shared__ short Bs[64 * 64];
  const int tid = threadIdx.x;
  const int w = tid >> 6, lane = tid & 63;
  const int la = lane >> 4, lb = lane & 15;
  const int wm = w & 1, wn = w >> 1;
  const int m0 = blockIdx.y << 7, n0 = blockIdx.x << 6;
  const int srow = lane >> 3;
  const int scol = ((lane & 7) ^ srow) << 3;
  const short* a0 = A + (size_t)(m0 + w * 32 + srow) * 1024 + scol;
  const short* b0 = W + (size_t)(n0 + w * 16 + srow) * 1024 + scol;
  short* lAw = As + (w * 32) * 64;
  short* lBw = Bs + (w * 16) * 64;

  f32x4 acc[4][2];
#pragma unroll
  for (int i = 0; i < 4; ++i)
#pragma unroll
    for (int j = 0; j < 2; ++j) acc[i][j] = (f32x4){0.f, 0.f, 0.f, 0.f};

  for (int k0 = 0; k0 < 1024; k0 += 64) {
    __syncthreads();
#pragma unroll
    for (int g = 0; g < 4; ++g) GLDS16(a0 + g * 8 * 1024 + k0, lAw + g * 8 * 64);
#pragma unroll
    for (int g = 0; g < 2; ++g) GLDS16(b0 + g * 8 * 1024 + k0, lBw + g * 8 * 64);
    __syncthreads();
#pragma unroll
    for (int ks = 0; ks < 2; ++ks) {
      bf16x8 af[4], bfr[2];
#pragma unroll
      for (int i = 0; i < 4; ++i) {
        const int row = wm * 64 + i * 16 + lb;
        af[i] = *(const bf16x8*)&As[row * 64 + (((ks << 2) + la) ^ (row & 7)) * 8];
      }
#pragma unroll
      for (int j = 0; j < 2; ++j) {
        const int row = wn * 32 + j * 16 + lb;
        bfr[j] = *(const bf16x8*)&Bs[row * 64 + (((ks << 2) + la) ^ (row & 7)) * 8];
      }
#pragma unroll
      for (int i = 0; i < 4; ++i)
#pragma unroll
        for (int j = 0; j < 2; ++j)
          acc[i][j] = __builtin_amdgcn_mfma_f32_16x16x32_bf16(af[i], bfr[j],
                                                              acc[i][j], 0, 0, 0);
    }
  }
#pragma unroll
  for (int j = 0; j < 2; ++j) {
    const int nj = n0 + wn * 32 + j * 16 + lb;
    const float bv = bias[nj];
#pragma unroll
    for (int i = 0; i < 4; ++i) {
      const int mi = m0 + wm * 64 + i * 16 + la * 4;
#pragma unroll
      for (int r = 0; r < 4; ++r)
        out[(size_t)(mi + r) * 1024 + nj] = acc[i][j][r] + bv;
    }
  }
}

// ---------------------------------------------------------------------------
// Flash attention v9 (best-measured variant, frozen): zero-LDS main loop,
// direct global->register K/V (fragment-blocked layouts), 2x-unrolled
// static ping-pong, setprio around MFMA clusters. 128 q-rows/block,
// 2wq x 2wk waves, grid (NH, SL/128, NB) = 512 blocks. 771 TF measured —
// occupancy/staging experiments (R0 LDS, R6-R8 occupancy) all null or
// regressive vs this form.
// ---------------------------------------------------------------------------
#define LOADK(DK, KB32)                                                      \
  do {                                                                       \
    _Pragma("unroll") for (int rr_ = 0; rr_ < 2; ++rr_)                      \
        _Pragma("unroll") for (int ks_ = 0; ks_ < 2; ++ks_)                  \
            DK[rr_][ks_] = *(const bf16x8*)(Kb + (size_t)(KB32) * 2048 +     \
                                            rr_ * 1024 + ks_ * 512);         \
  } while (0)

#define LOADV(DV, KB32)                                                      \
  do {                                                                       \
    _Pragma("unroll") for (int md_ = 0; md_ < 4; ++md_)                      \
        DV[md_] = *(const bf16x8*)(Vb + (size_t)(KB32) * 2048 + md_ * 512);  \
  } while (0)

#define ATTN_STEP(AK, AV)                                                    \
  do {                                                                       \
    f32x4 S[2][4];                                                           \
    _Pragma("unroll") for (int mt = 0; mt < 2; ++mt)                         \
        _Pragma("unroll") for (int nt = 0; nt < 4; ++nt)                     \
            S[mt][nt] = (f32x4){0.f, 0.f, 0.f, 0.f};                         \
    __builtin_amdgcn_s_setprio(1);                                           \
    _Pragma("unroll") for (int ks = 0; ks < 2; ++ks)                         \
        _Pragma("unroll") for (int nt = 0; nt < 4; ++nt) {                   \
      S[0][nt] = __builtin_amdgcn_mfma_f32_16x16x32_bf16(AK[0][ks],          \
                     bQ[nt][ks], S[0][nt], 0, 0, 0);                         \
      S[1][nt] = __builtin_amdgcn_mfma_f32_16x16x32_bf16(AK[1][ks],          \
                     bQ[nt][ks], S[1][nt], 0, 0, 0);                         \
    }                                                                        \
    __builtin_amdgcn_s_setprio(0);                                           \
    _Pragma("unroll") for (int nt = 0; nt < 4; ++nt) {                       \
      _Pragma("unroll") for (int mt = 0; mt < 2; ++mt)                       \
          _Pragma("unroll") for (int r = 0; r < 4; ++r) {                    \
        const float p = __builtin_amdgcn_exp2f(S[mt][nt][r]);                \
        S[mt][nt][r] = p;                                                    \
        lacc[nt] += p;                                                       \
      }                                                                      \
      bf16x8 B2;                                                             \
      B2[0] = f2b(S[0][nt][0]); B2[1] = f2b(S[0][nt][1]);                    \
      B2[2] = f2b(S[0][nt][2]); B2[3] = f2b(S[0][nt][3]);                    \
      B2[4] = f2b(S[1][nt][0]); B2[5] = f2b(S[1][nt][1]);                    \
      B2[6] = f2b(S[1][nt][2]); B2[7] = f2b(S[1][nt][3]);                    \
      __builtin_amdgcn_s_setprio(1);                                         \
      _Pragma("unroll") for (int mtd = 0; mtd < 4; ++mtd)                    \
          O[mtd][nt] = __builtin_amdgcn_mfma_f32_16x16x32_bf16(              \
              AV[mtd], B2, O[mtd][nt], 0, 0, 0);                             \
      __builtin_amdgcn_s_setprio(0);                                         \
    }                                                                        \
  } while (0)

__global__ __launch_bounds__(256, 2) void attn_mfma(const short* __restrict__ Qg,
                                                    const short* __restrict__ Kp,
                                                    const short* __restrict__ Vp,
                                                    short* __restrict__ Ab) {
  __shared__ __align__(16) float red[2][64][68];  // 34816 B
  __shared__ float lred[128];
  const int tid = threadIdx.x;
  const int w = tid >> 6, lane = tid & 63;
  const int G = lane >> 4, lb = lane & 15;
  const int wk = w & 1, wq = w >> 1;
  const int h = blockIdx.x, qt = blockIdx.y, n = blockIdx.z;

  // ---- Q fragments: global -> regs, once. q = 64wq+16nt+lb, d = 32ks+8G
  const short* Qb = Qg + ((size_t)(n * SL + (qt << 7) + 64 * wq)) * EMB + h * HD;
  bf16x8 bQ[4][2];
#pragma unroll
  for (int nt = 0; nt < 4; ++nt)
#pragma unroll
    for (int ks = 0; ks < 2; ++ks)
      bQ[nt][ks] =
          *(const bf16x8*)(Qb + (size_t)(16 * nt + lb) * EMB + 32 * ks + 8 * G);

  f32x4 O[4][4];  // [mtd: d=16mtd+4G+r][nt: q=64wq+16nt+lb]
  float lacc[4] = {0.f, 0.f, 0.f, 0.f};
#pragma unroll
  for (int i = 0; i < 4; ++i)
#pragma unroll
    for (int j = 0; j < 4; ++j) O[i][j] = (f32x4){0.f, 0.f, 0.f, 0.f};

  // fragment-blocked bases; fold per-lane 16B chunk offset into the pointer
  const short* Kb = Kp + (((size_t)(n * NH + h)) << 17) + lane * 8;
  const short* Vb = Vp + (((size_t)(n * NH + h)) << 17) + lane * 8;

  // wave wk owns 32-key blocks kb32 = 4j + 2wk + {0,1}; 2x-unrolled ping-pong
  bf16x8 K0[2][2], V0[4], K1[2][2], V1[4];
  LOADK(K0, 2 * wk);
  LOADV(V0, 2 * wk);
  for (int it = 0; it < 32; it += 2) {
    const int kA = 2 * it + 2 * wk;  // even sub-round's kb32
    LOADK(K1, kA + 1);
    LOADV(V1, kA + 1);
    ATTN_STEP(K0, V0);
    if (it + 2 < 32) {
      LOADK(K0, kA + 4);
      LOADV(V0, kA + 4);
    }
    ATTN_STEP(K1, V1);
  }

  // ---- finish l: reduce across G groups (sum over this wave's keys)
#pragma unroll
  for (int nt = 0; nt < 4; ++nt) {
    lacc[nt] += __shfl_xor(lacc[nt], 16);
    lacc[nt] += __shfl_xor(lacc[nt], 32);
  }

  // ---- 2-way cross-wave reduction over wk (dedicated LDS, one barrier)
  if (wk == 1) {
#pragma unroll
    for (int nt = 0; nt < 4; ++nt) {
      const int q = 16 * nt + lb;
#pragma unroll
      for (int mtd = 0; mtd < 4; ++mtd)
        *(f32x4*)&red[wq][q][16 * mtd + 4 * G] = O[mtd][nt];
      if (G == 0) lred[wq * 64 + q] = lacc[nt];
    }
  }
  __syncthreads();
  if (wk == 0) {
    short* Ao = Ab + ((size_t)(n * SL + (qt << 7) + 64 * wq)) * EMB + h * HD;
#pragma unroll
    for (int nt = 0; nt < 4; ++nt) {
      const int q = 16 * nt + lb;
      const float inv = 1.f / (lacc[nt] + lred[wq * 64 + q]);
#pragma unroll
      for (int mtd = 0; mtd < 4; ++mtd) {
        const f32x4 t = *(const f32x4*)&red[wq][q][16 * mtd + 4 * G];
        const f32x4 s = t + O[mtd][nt];
        const short4 o = {f2b(s[0] * inv), f2b(s[1] * inv), f2b(s[2] * inv),
                          f2b(s[3] * inv)};
        *(short4*)(Ao + (size_t)q * EMB + 16 * mtd + 4 * G) = o;
      }
    }
  }
}

extern "C" void kernel_launch(void* const* d_in, const int* in_sizes, int n_in,
                              void* d_out, int out_size, void* d_ws, size_t ws_size,
                              hipStream_t stream) {
  const float* x  = (const float*)d_in[0];
  const float* Wq = (const float*)d_in[1];
  const float* Wk = (const float*)d_in[2];
  const float* Wv = (const float*)d_in[3];
  const float* Wo = (const float*)d_in[4];
  const float* bo = (const float*)d_in[5];
  float* out = (float*)d_out;

  // ws (bf16 elements): xb 4M | wqkv 3M | wob 1M | qb 4M | kb 4M | vt 4M = 40 MB
  short* xb   = (short*)d_ws;
  short* wqkv = xb + PROJ;
  short* wob  = wqkv + 3u * EMB * EMB;
  short* qb   = wob + (size_t)EMB * EMB;
  short* kb   = qb + PROJ;
  short* vt   = kb + PROJ;
  short* ab   = qb;  // alias: block-disjoint read-then-write regions

  cast_all<<<8192, 256, 0, stream>>>(x, Wq, Wk, Wv, Wo, xb, wqkv, wob);
  gemm_qkv<<<dim3(24, 32), 256, 0, stream>>>(xb, wqkv, qb, kb, vt);
  attn_mfma<<<dim3(NH, SL / 128, NB), 256, 0, stream>>>(qb, kb, vt, ab);
  gemm_out<<<dim3(16, 32), 256, 0, stream>>>(ab, wob, bo, out);
}